// Round 15
// baseline (124.021 us; speedup 1.0000x reference)
//
#include <hip/hip_runtime.h>

// GraphSAGE 2-layer, N=100000, E=1000000, 64 -> 128 -> 64.
// Round 15: mega-fusion. Bucket (128 dst nodes) == gemm1 tile (128 rows):
//   sort_gather_gemm1 = per-bucket LDS counting sort + gather into LDS A-tile
//                       + MFMA. agg1b never exists in HBM.
//   prep_all          = x->bf16 + W prep + zero rows + bucketize (fused).
// 5 launches: memset gcnt; prep_all; sort_gather_gemm1; gemm2; agg_add.

#define NPB 128       // nodes per bucket (dst >> 7)
#define NBK 782       // ceil(100000/128)
#define BCAP_E 1600   // raw bucket capacity; mean 1279, sd 36 -> +9 sigma
#define BCAP_S 2048   // sorted+padded capacity; hard-clamped

typedef __attribute__((ext_vector_type(8))) short bf16x8;
typedef __attribute__((ext_vector_type(4))) float f32x4;
typedef __attribute__((ext_vector_type(4))) int int4v;

__device__ __forceinline__ float bf2f(unsigned short u) {
  return __uint_as_float(((unsigned)u) << 16);
}
__device__ __forceinline__ unsigned short f2bf(float f) {
  unsigned x = __float_as_uint(f);
  x += 0x7fffu + ((x >> 16) & 1u);   // RNE
  return (unsigned short)(x >> 16);
}

// ------- prep_all: convert_bf16 | W prep | zero rows | bucketize -------
// gcnt must be zeroed BEFORE this kernel (memsetAsync) since bucketize
// blocks run concurrently with everything else here.
__global__ __launch_bounds__(256) void prep_all(
    const float* __restrict__ x, unsigned short* __restrict__ xb, int total4,
    const float* __restrict__ Wl1, const float* __restrict__ Wr1,
    const float* __restrict__ Wl2, const float* __restrict__ Wr2,
    unsigned short* __restrict__ Wt1, unsigned short* __restrict__ Wcat,
    unsigned short* __restrict__ tzero,
    const int* __restrict__ src, const int* __restrict__ dst,
    int* __restrict__ gcnt, int* __restrict__ ebuf, int e,
    int n, int CB) {
  __shared__ int lcnt[NBK], lbase[NBK];
  int b = blockIdx.x;
  if (b < CB) {
    int i = b * 256 + threadIdx.x;
    if (i < total4) {
      float4 v = ((const float4*)x)[i];
      ushort4 o;
      o.x = f2bf(v.x); o.y = f2bf(v.y); o.z = f2bf(v.z); o.w = f2bf(v.w);
      ((ushort4*)xb)[i] = o;
    }
    return;
  }
  if (b < CB + 128) {
    int o = (b - CB) * 256 + threadIdx.x;   // 0..32767
    if (o < 16384) {
      int m = o >> 13, rem = o & 8191;
      int col = rem >> 6, k = rem & 63;
      const float* W = m ? Wr1 : Wl1;
      Wt1[o] = f2bf(W[k * 128 + col]);
    } else {
      int o2 = o - 16384;
      int col = o2 >> 7, k = o2 & 127;
      float v = (col < 64) ? Wl2[k * 64 + col] : Wr2[k * 64 + col - 64];
      Wcat[o2] = f2bf(v);
    }
    return;
  }
  if (b < CB + 129) {
    // zero feature rows at index n (gather pad target)
    if (threadIdx.x < 32) {
      ((unsigned*)(xb + (size_t)n * 64))[threadIdx.x] = 0;
      ((unsigned*)(tzero + (size_t)n * 64))[threadIdx.x] = 0;
    }
    return;
  }
  // ---- bucketize blocks ----
  int bb = b - (CB + 129);
  for (int i = threadIdx.x; i < NBK; i += 256) lcnt[i] = 0;
  __syncthreads();
  int pk[16], bk[16];
  int nv = 0;
  int base = bb * 4096 + threadIdx.x * 4;
#pragma unroll
  for (int c = 0; c < 4; ++c) {
    int i = base + c * 1024;
    if (i + 4 <= e) {
      int4v sv = *(const int4v*)(src + i);
      int4v dv = *(const int4v*)(dst + i);
#pragma unroll
      for (int j = 0; j < 4; ++j) {
        bk[nv] = dv[j] >> 7;
        pk[nv] = ((dv[j] & 127) << 17) | sv[j];
        ++nv;
      }
    } else if (i < e) {
      for (int i2 = i; i2 < e; ++i2) {
        int dj = dst[i2], sj = src[i2];
        bk[nv] = dj >> 7;
        pk[nv] = ((dj & 127) << 17) | sj;
        ++nv;
      }
    }
  }
  for (int k = 0; k < nv; ++k) atomicAdd(&lcnt[bk[k]], 1);
  __syncthreads();
  for (int i = threadIdx.x; i < NBK; i += 256) {
    lbase[i] = atomicAdd(&gcnt[i], lcnt[i]);
    lcnt[i] = 0;   // reuse as cursor
  }
  __syncthreads();
  for (int k = 0; k < nv; ++k) {
    int off = lbase[bk[k]] + atomicAdd(&lcnt[bk[k]], 1);
    if (off < BCAP_E) ebuf[bk[k] * BCAP_E + off] = pk[k];
  }
}

// ------- sort_gather_gemm1: per-bucket sort + gather + MFMA -------
// 512 threads (8 waves). Bucket b == output rows b*128..b*128+128.
// LDS: sW 32KB | sA 16KB | sorted 8KB | sort meta ~1.5KB  => 2 blocks/CU.
__global__ __launch_bounds__(512) void sort_gather_gemm1(
    const unsigned short* __restrict__ xb, const int* __restrict__ gcnt,
    const int* __restrict__ ebuf, const unsigned short* __restrict__ Wt1,
    const float* __restrict__ b1,
    int* __restrict__ srcS, int* __restrict__ nstart, int* __restrict__ ncnt,
    unsigned short* __restrict__ h, int n) {
  __shared__ unsigned short sW[16384];   // 2 x [128 col][64 k], 16B-XOR swizzled
  __shared__ unsigned short sA[8192];    // [128 row][64 ch], 16B-XOR swizzled
  __shared__ int sorted[BCAP_S];
  __shared__ int cnt[NPB], cur[NPB], st[NPB + 1];
  int tid = threadIdx.x, lane = tid & 63, wid = tid >> 6;
  int l15 = lane & 15, g = lane >> 4;
  int b = blockIdx.x;

  // stage W early (global loads overlap the sort)
#pragma unroll
  for (int it = 0; it < 4; ++it) {
    int i = it * 512 + tid;                 // 2048 16B chunks
    int byte = i << 4;
    int col = (byte >> 7) & 127;
    int koff = (byte & 127) ^ ((col & 7) << 4);
    int dstb = (byte & ~127) | koff;
    bf16x8 v = *(const bf16x8*)(Wt1 + i * 8);
    *(bf16x8*)((char*)sW + dstb) = v;
  }
  float bj[8];
#pragma unroll
  for (int cb = 0; cb < 8; ++cb) bj[cb] = b1[cb * 16 + l15];

  // ---- counting sort ----
  if (tid < NPB) { cnt[tid] = 0; cur[tid] = 0; }
  __syncthreads();
  int ecnt = min(gcnt[b], BCAP_E);
  const int* eb = ebuf + b * BCAP_E;
  for (int i = tid; i < ecnt; i += 512) atomicAdd(&cnt[eb[i] >> 17], 1);
  __syncthreads();
  if (wid == 0) {   // exclusive scan of 128 PADDED counts with one wave
    int i0 = (cnt[lane] + 3) & ~3, i1 = (cnt[64 + lane] + 3) & ~3;
#pragma unroll
    for (int off = 1; off < 64; off <<= 1) {
      int u = __shfl_up(i0, off);
      if (lane >= off) i0 += u;
    }
    int t0 = __shfl(i0, 63);
#pragma unroll
    for (int off = 1; off < 64; off <<= 1) {
      int u = __shfl_up(i1, off);
      if (lane >= off) i1 += u;
    }
    st[lane + 1] = i0;
    st[64 + lane + 1] = t0 + i1;
    if (lane == 0) st[0] = 0;
  }
  __syncthreads();
  for (int i = tid; i < ecnt; i += 512) {
    int pk = eb[i];
    int dl = pk >> 17;
    int pos = st[dl] + atomicAdd(&cur[dl], 1);
    if (pos < BCAP_S) sorted[pos] = pk & 0x1FFFF;
  }
  __syncthreads();
  if (tid < NPB) {   // pad fill with zero-row index + meta for layer 2
    int c = cnt[tid], p = (c + 3) & ~3;
    int base = st[tid];
    for (int k = c; k < p; ++k)
      if (base + k < BCAP_S) sorted[base + k] = n;
    int node = b * NPB + tid;
    if (node < n) {
      nstart[node] = b * BCAP_S + base;
      ncnt[node] = c;
    }
  }
  __syncthreads();
  // coalesced srcS dump for agg_add (layer 2)
  int total = min(st[NPB], BCAP_S);
  for (int i = tid; i < total; i += 512) srcS[b * BCAP_S + i] = sorted[i];

  // ---- gather into sA: 8 waves x 2 nodes x 8 passes ----
  {
    int half32 = lane & 32;
    int hlane = lane & 31;
    int gg = hlane >> 3;
    int ch8 = lane & 7;
#pragma unroll 1
    for (int pass = 0; pass < 8; ++pass) {
      int dl = pass * 16 + wid * 2 + (lane >> 5);   // 0..127
      int s = st[dl], c = cnt[dl];
      int dpad = (c + 3) & ~3;
      float acc[8];
#pragma unroll
      for (int j = 0; j < 8; ++j) acc[j] = 0.f;
      int nit = dpad >> 2;
      int nitw = max(nit, __shfl_xor(nit, 32));
      int idx = (s + hlane < BCAP_S) ? sorted[s + hlane] : n;
      bf16x8 cch[8];
#pragma unroll
      for (int u = 0; u < 8; ++u) {
        if (u < nitw) {
          int r = u * 4 + gg;
          int sidx = __shfl(idx, half32 + r);
          if (u < nit) cch[u] = *(const bf16x8*)(xb + (size_t)sidx * 64 + ch8 * 8);
        }
      }
#pragma unroll
      for (int u = 0; u < 8; ++u) {
        if (u < nitw && u < nit) {
#pragma unroll
          for (int j = 0; j < 8; ++j) acc[j] += bf2f((unsigned short)cch[u][j]);
        }
      }
      for (int b0 = 32; b0 < dpad; b0 += 32) {   // rare: deg > 32
        int idx2 = (s + b0 + hlane < BCAP_S) ? sorted[s + b0 + hlane] : n;
#pragma unroll
        for (int u = 0; u < 8; ++u) {
          int r = u * 4 + gg;
          if (b0 + r < dpad) {
            int sidx = __shfl(idx2, half32 + r);
            bf16x8 v = *(const bf16x8*)(xb + (size_t)sidx * 64 + ch8 * 8);
#pragma unroll
            for (int j = 0; j < 8; ++j) acc[j] += bf2f((unsigned short)v[j]);
          }
        }
      }
#pragma unroll
      for (int m = 8; m < 32; m <<= 1) {
#pragma unroll
        for (int j = 0; j < 8; ++j) acc[j] += __shfl_xor(acc[j], m);
      }
      if (hlane < 8) {
        float inv = 1.f / (float)max(c, 1);
        bf16x8 o;
#pragma unroll
        for (int j = 0; j < 8; ++j) o[j] = (short)f2bf(acc[j] * inv);
        int byte = dl * 128 + ((ch8 * 16) ^ ((dl & 7) << 4));
        *(bf16x8*)((char*)sA + byte) = o;
      }
    }
  }
  __syncthreads();

  // ---- MFMA: wave wid -> rows wid*16..+16, all 128 cols ----
  int rowl = wid * 16 + l15;                 // row in sA / tile
  int growbase = b * 128 + wid * 16;
  size_t cr = (size_t)min(growbase + l15, n - 1);

  f32x4 acc[8];
#pragma unroll
  for (int cb = 0; cb < 8; ++cb) acc[cb] = (f32x4){0.f, 0.f, 0.f, 0.f};

#pragma unroll
  for (int m = 0; m < 2; ++m) {
#pragma unroll
    for (int s = 0; s < 2; ++s) {
      int ko = s * 64 + g * 16;
      bf16x8 a;
      if (m == 0) {
        int koff = ko ^ ((rowl & 7) << 4);
        a = *(const bf16x8*)((const char*)sA + rowl * 128 + koff);
      } else {
        a = *(const bf16x8*)((const char*)xb + cr * 128 + ko);
      }
#pragma unroll
      for (int cb = 0; cb < 8; ++cb) {
        int col = cb * 16 + l15;
        int koff = ko ^ ((col & 7) << 4);
        bf16x8 bb = *(const bf16x8*)((const char*)sW + m * 16384 + col * 128 + koff);
        acc[cb] = __builtin_amdgcn_mfma_f32_16x16x32_bf16(a, bb, acc[cb], 0, 0, 0);
      }
    }
  }
  // epilogue: D col = l15, row = g*4 + r
  int rb = growbase + g * 4;
#pragma unroll
  for (int r = 0; r < 4; ++r) {
    int row = rb + r;
    if (row < n) {
      unsigned short* hp = h + (size_t)row * 128 + l15;
#pragma unroll
      for (int cb = 0; cb < 8; ++cb) {
        float v = fmaxf(acc[cb][r] + bj[cb], 0.f);
        hp[cb * 16] = f2bf(v);
      }
    }
  }
}

// ---------------- layer 2 MFMA: [t | out] = h @ [Wl2 | Wr2] ----------------
__global__ __launch_bounds__(256) void gemm2_mfma(
    const unsigned short* __restrict__ h, const unsigned short* __restrict__ Wcat,
    const float* __restrict__ b2, unsigned short* __restrict__ t,
    float* __restrict__ outp, int n) {
  __shared__ unsigned short sW[16384];  // 32KB: [128 col][128 k], swizzled
  int tid = threadIdx.x;
  int lane = tid & 63, wid = tid >> 6;
  int l15 = lane & 15, g = lane >> 4;
#pragma unroll
  for (int it = 0; it < 8; ++it) {
    int i = it * 256 + tid;
    int byte = i << 4;
    int col = byte >> 8;
    int koff = (byte & 255) ^ ((col & 15) << 4);
    int dstb = (byte & ~255) | koff;
    bf16x8 v = *(const bf16x8*)(Wcat + i * 8);
    *(bf16x8*)((char*)sW + dstb) = v;
  }
  float bj[4];
#pragma unroll
  for (int cb = 0; cb < 4; ++cb) bj[cb] = b2[cb * 16 + l15];
  __syncthreads();

  int rowbase = blockIdx.x * 128 + wid * 32;
  int r0 = rowbase + l15, r1 = r0 + 16;
  size_t cr0 = (size_t)min(r0, n - 1), cr1 = (size_t)min(r1, n - 1);

  f32x4 acc[2][8];
#pragma unroll
  for (int fr = 0; fr < 2; ++fr)
#pragma unroll
    for (int cb = 0; cb < 8; ++cb) acc[fr][cb] = (f32x4){0.f, 0.f, 0.f, 0.f};

  const char* hb = (const char*)h;
#pragma unroll
  for (int s = 0; s < 4; ++s) {
    int ko = s * 64 + g * 16;
    bf16x8 a0 = *(const bf16x8*)(hb + cr0 * 256 + ko);
    bf16x8 a1 = *(const bf16x8*)(hb + cr1 * 256 + ko);
#pragma unroll
    for (int cb = 0; cb < 8; ++cb) {
      int col = cb * 16 + l15;
      int koff = ko ^ ((col & 15) << 4);
      bf16x8 b = *(const bf16x8*)((const char*)sW + col * 256 + koff);
      acc[0][cb] = __builtin_amdgcn_mfma_f32_16x16x32_bf16(a0, b, acc[0][cb], 0, 0, 0);
      acc[1][cb] = __builtin_amdgcn_mfma_f32_16x16x32_bf16(a1, b, acc[1][cb], 0, 0, 0);
    }
  }
#pragma unroll
  for (int fr = 0; fr < 2; ++fr) {
    int rb = rowbase + fr * 16 + g * 4;
#pragma unroll
    for (int r = 0; r < 4; ++r) {
      int row = rb + r;
      if (row < n) {
#pragma unroll
        for (int cb = 0; cb < 4; ++cb)
          t[(size_t)row * 64 + cb * 16 + l15] = f2bf(acc[fr][cb][r]);
#pragma unroll
        for (int cb = 0; cb < 4; ++cb)
          outp[(size_t)row * 64 + cb * 16 + l15] = acc[fr][cb + 4][r] + bj[cb];
      }
    }
  }
}

// ------- 2-nodes-per-wave segment-mean gather (layer 2 add) -------
__device__ __forceinline__ void gather2(
    const unsigned short* __restrict__ feat, const int* __restrict__ srcS,
    int s, int dpad, int lane, float* acc) {
  int half32 = lane & 32;
  int hlane = lane & 31;
  int g = hlane >> 3;
  int ch8 = lane & 7;
#pragma unroll
  for (int j = 0; j < 8; ++j) acc[j] = 0.f;
  int nit = dpad >> 2;
  int nitw = max(nit, __shfl_xor(nit, 32));
  int idx = srcS[s + hlane];
  bf16x8 c[8];
#pragma unroll
  for (int u = 0; u < 8; ++u) {
    if (u < nitw) {
      int r = u * 4 + g;
      int sidx = __shfl(idx, half32 + r);
      if (u < nit) c[u] = *(const bf16x8*)(feat + (size_t)sidx * 64 + ch8 * 8);
    }
  }
#pragma unroll
  for (int u = 0; u < 8; ++u) {
    if (u < nitw && u < nit) {
#pragma unroll
      for (int j = 0; j < 8; ++j) acc[j] += bf2f((unsigned short)c[u][j]);
    }
  }
  for (int b0 = 32; b0 < dpad; b0 += 32) {
    int idx2 = srcS[s + b0 + hlane];
#pragma unroll
    for (int u = 0; u < 8; ++u) {
      int r = u * 4 + g;
      if (b0 + r < dpad) {
        int sidx = __shfl(idx2, half32 + r);
        bf16x8 v = *(const bf16x8*)(feat + (size_t)sidx * 64 + ch8 * 8);
#pragma unroll
        for (int j = 0; j < 8; ++j) acc[j] += bf2f((unsigned short)v[j]);
      }
    }
  }
#pragma unroll
  for (int m = 8; m < 32; m <<= 1) {
#pragma unroll
    for (int j = 0; j < 8; ++j) acc[j] += __shfl_xor(acc[j], m);
  }
}

__global__ __launch_bounds__(256) void agg_add_fast(
    const unsigned short* __restrict__ feat, const int* __restrict__ nstart,
    const int* __restrict__ ncnt, const int* __restrict__ srcS,
    float* __restrict__ outp, int n) {
  int lane = threadIdx.x & 63, wid = threadIdx.x >> 6;
  int half = lane >> 5;
  int node = (blockIdx.x * 4 + wid) * 2 + half;
  bool live = node < n;
  int cn = live ? node : n - 1;
  int s = nstart[cn];
  int c = ncnt[cn];
  int dpad = (c + 3) & ~3;
  float acc[8];
  gather2(feat, srcS, s, dpad, lane, acc);
  float inv = 1.f / (float)max(c, 1);
  if ((lane & 31) < 8 && live) {
    float4* op = (float4*)(outp + (size_t)node * 64 + (lane & 7) * 8);
    float4 o0 = op[0], o1 = op[1];
    o0.x += acc[0] * inv; o0.y += acc[1] * inv;
    o0.z += acc[2] * inv; o0.w += acc[3] * inv;
    o1.x += acc[4] * inv; o1.y += acc[5] * inv;
    o1.z += acc[6] * inv; o1.w += acc[7] * inv;
    op[0] = o0; op[1] = o1;
  }
}

extern "C" void kernel_launch(void* const* d_in, const int* in_sizes, int n_in,
                              void* d_out, int out_size, void* d_ws, size_t ws_size,
                              hipStream_t stream) {
  const float* x   = (const float*)d_in[0];
  const int*   ei  = (const int*)d_in[1];
  const float* Wl1 = (const float*)d_in[2];
  const float* b1  = (const float*)d_in[3];
  const float* Wr1 = (const float*)d_in[4];
  const float* Wl2 = (const float*)d_in[5];
  const float* b2  = (const float*)d_in[6];
  const float* Wr2 = (const float*)d_in[7];
  float* out = (float*)d_out;

  const int n = in_sizes[0] / 64;   // 100000
  const int e = in_sizes[1] / 2;    // 1000000
  const int* src = ei;
  const int* dst = ei + e;

  char* ws = (char*)d_ws;
  size_t off = 0;
  auto take = [&](size_t bytes) { void* p = ws + off; off = (off + bytes + 255) & ~(size_t)255; return p; };
  int*            gcnt   = (int*)take((size_t)NBK * 4);
  int*            ebuf   = (int*)take((size_t)NBK * BCAP_E * 4);       // 5.0 MB
  int*            srcS   = (int*)take((size_t)NBK * BCAP_S * 4 + 256); // 6.4 MB
  int*            nstart = (int*)take((size_t)n * 4);
  int*            ncnt   = (int*)take((size_t)n * 4);
  unsigned short* xb     = (unsigned short*)take(((size_t)n + 1) * 64 * 2);  // +zero row
  unsigned short* t      = (unsigned short*)take(((size_t)n + 1) * 64 * 2);  // +zero row
  unsigned short* h      = (unsigned short*)take((size_t)n * 128 * 2);
  unsigned short* Wt1    = (unsigned short*)take(16384 * 2);
  unsigned short* Wcat   = (unsigned short*)take(16384 * 2);

  const int total4 = n * 64 / 4;         // 1.6M
  const int CB = (total4 + 255) / 256;   // 6250
  const int EB2 = (e + 4095) / 4096;     // 245

  // 1) zero gcnt (bucketize runs inside prep_all)
  (void)hipMemsetAsync(gcnt, 0, (size_t)NBK * 4, stream);
  // 2) prep_all: convert | W prep | zero rows | bucketize
  prep_all<<<CB + 129 + EB2, 256, 0, stream>>>(x, xb, total4,
                                               Wl1, Wr1, Wl2, Wr2, Wt1, Wcat,
                                               t, src, dst, gcnt, ebuf, e, n, CB);
  // 3) layer 1 fused: sort + gather + gemm1
  sort_gather_gemm1<<<NBK, 512, 0, stream>>>(xb, gcnt, ebuf, Wt1, b1,
                                             srcS, nstart, ncnt, h, n);
  // 4) layer 2 GEMM
  gemm2_mfma<<<NBK, 256, 0, stream>>>(h, Wcat, b2, t, out, n);
  // 5) layer 2 aggregation add
  agg_add_fast<<<(n + 7) / 8, 256, 0, stream>>>(t, nstart, ncnt, srcS, out, n);
}

// Round 16
// 123.524 us; speedup vs baseline: 1.0040x; 1.0040x over previous
//
#include <hip/hip_runtime.h>

// GraphSAGE 2-layer, N=100000, E=1000000, 64 -> 128 -> 64.
// Round 16: round-14 pipeline + gather/gemm1 fusion only (no sort in-kernel).
//  1) fused_misc : x->bf16, W prep, gcnt zero, zero rows
//  2) bucketize  : edges -> 782 buckets of 128 dst nodes, packed (dl<<17|src)
//  3) sort_write : LDS counting sort + pad-to-x4 -> srcS, nstart, ncnt
//  4) gather_gemm1: per bucket, gather(xb) -> LDS A-tile -> MFMA -> h
//  5) gemm2_mfma : {t, out} = h @ [Wl2 | Wr2] (+b2)
//  6) agg_add    : out += mean-gather(t)

#define NPB 128       // nodes per bucket (dst >> 7)
#define NBK 782       // ceil(100000/128)
#define BCAP_E 1600   // raw bucket capacity; mean 1279, sd 36 -> +9 sigma
#define BCAP_S 2048   // sorted+padded capacity; hard-clamped

typedef __attribute__((ext_vector_type(8))) short bf16x8;
typedef __attribute__((ext_vector_type(4))) float f32x4;
typedef __attribute__((ext_vector_type(4))) int int4v;

__device__ __forceinline__ float bf2f(unsigned short u) {
  return __uint_as_float(((unsigned)u) << 16);
}
__device__ __forceinline__ unsigned short f2bf(float f) {
  unsigned x = __float_as_uint(f);
  x += 0x7fffu + ((x >> 16) & 1u);   // RNE
  return (unsigned short)(x >> 16);
}

// ------- fused prep: convert_bf16 + prep_w + gcnt zero + zero rows -------
__global__ __launch_bounds__(256) void fused_misc(
    const float* __restrict__ x, unsigned short* __restrict__ xb, int total4,
    const float* __restrict__ Wl1, const float* __restrict__ Wr1,
    const float* __restrict__ Wl2, const float* __restrict__ Wr2,
    unsigned short* __restrict__ Wt1, unsigned short* __restrict__ Wcat,
    int* __restrict__ gcnt, unsigned short* __restrict__ tzero,
    int n, int CB) {
  int b = blockIdx.x;
  if (b < CB) {
    int i = b * 256 + threadIdx.x;
    if (i < total4) {
      float4 v = ((const float4*)x)[i];
      ushort4 o;
      o.x = f2bf(v.x); o.y = f2bf(v.y); o.z = f2bf(v.z); o.w = f2bf(v.w);
      ((ushort4*)xb)[i] = o;
    }
  } else if (b < CB + 128) {
    int o = (b - CB) * 256 + threadIdx.x;   // 0..32767
    if (o < 16384) {
      int m = o >> 13, rem = o & 8191;
      int col = rem >> 6, k = rem & 63;
      const float* W = m ? Wr1 : Wl1;
      Wt1[o] = f2bf(W[k * 128 + col]);
    } else {
      int o2 = o - 16384;
      int col = o2 >> 7, k = o2 & 127;
      float v = (col < 64) ? Wl2[k * 64 + col] : Wr2[k * 64 + col - 64];
      Wcat[o2] = f2bf(v);
    }
  } else {
    for (int i = threadIdx.x; i < NBK; i += 256) gcnt[i] = 0;
    // zero feature rows at index n (gather pad target); survive: only
    // rows < n are rewritten afterwards.
    if (threadIdx.x < 32) {
      ((unsigned*)(xb + (size_t)n * 64))[threadIdx.x] = 0;
      ((unsigned*)(tzero + (size_t)n * 64))[threadIdx.x] = 0;
    }
  }
}

// ---------------- bucketize: edges -> 782 buckets, packed 4B ----------------
__global__ __launch_bounds__(256) void bucketize(
    const int* __restrict__ src, const int* __restrict__ dst,
    int* __restrict__ gcnt, int* __restrict__ ebuf, int e) {
  __shared__ int lcnt[NBK], lbase[NBK];
  for (int i = threadIdx.x; i < NBK; i += 256) lcnt[i] = 0;
  __syncthreads();
  int pk[16], bk[16];
  int nv = 0;
  int base = blockIdx.x * 4096 + threadIdx.x * 4;
#pragma unroll
  for (int c = 0; c < 4; ++c) {
    int i = base + c * 1024;
    if (i + 4 <= e) {
      int4v sv = *(const int4v*)(src + i);
      int4v dv = *(const int4v*)(dst + i);
#pragma unroll
      for (int j = 0; j < 4; ++j) {
        bk[nv] = dv[j] >> 7;
        pk[nv] = ((dv[j] & 127) << 17) | sv[j];
        ++nv;
      }
    } else if (i < e) {
      for (int i2 = i; i2 < e; ++i2) {
        int dj = dst[i2], sj = src[i2];
        bk[nv] = dj >> 7;
        pk[nv] = ((dj & 127) << 17) | sj;
        ++nv;
      }
    }
  }
  for (int k = 0; k < nv; ++k) atomicAdd(&lcnt[bk[k]], 1);
  __syncthreads();
  for (int i = threadIdx.x; i < NBK; i += 256) {
    lbase[i] = atomicAdd(&gcnt[i], lcnt[i]);
    lcnt[i] = 0;   // reuse as cursor
  }
  __syncthreads();
  for (int k = 0; k < nv; ++k) {
    int off = lbase[bk[k]] + atomicAdd(&lcnt[bk[k]], 1);
    if (off < BCAP_E) ebuf[bk[k] * BCAP_E + off] = pk[k];
  }
}

// ------- sort_write: LDS counting sort + pad-to-x4 -> global CSR -------
__global__ __launch_bounds__(256) void sort_write(
    const int* __restrict__ gcnt, const int* __restrict__ ebuf,
    int* __restrict__ srcS, int* __restrict__ nstart, int* __restrict__ ncnt,
    int n) {
  __shared__ int cnt[NPB], cur[NPB], st[NPB + 1], sorted[BCAP_S];
  int tid = threadIdx.x, lane = tid & 63, wid = tid >> 6;
  int b = blockIdx.x;
  if (tid < NPB) { cnt[tid] = 0; cur[tid] = 0; }
  __syncthreads();
  int ecnt = min(gcnt[b], BCAP_E);
  const int* eb = ebuf + b * BCAP_E;
  for (int i = tid; i < ecnt; i += 256) atomicAdd(&cnt[eb[i] >> 17], 1);
  __syncthreads();
  if (wid == 0) {   // exclusive scan of 128 PADDED counts with one wave
    int i0 = (cnt[lane] + 3) & ~3, i1 = (cnt[64 + lane] + 3) & ~3;
#pragma unroll
    for (int off = 1; off < 64; off <<= 1) {
      int u = __shfl_up(i0, off);
      if (lane >= off) i0 += u;
    }
    int t0 = __shfl(i0, 63);
#pragma unroll
    for (int off = 1; off < 64; off <<= 1) {
      int u = __shfl_up(i1, off);
      if (lane >= off) i1 += u;
    }
    st[lane + 1] = i0;
    st[64 + lane + 1] = t0 + i1;
    if (lane == 0) st[0] = 0;
  }
  __syncthreads();
  for (int i = tid; i < ecnt; i += 256) {
    int pk = eb[i];
    int dl = pk >> 17;
    int pos = st[dl] + atomicAdd(&cur[dl], 1);
    if (pos < BCAP_S) sorted[pos] = pk & 0x1FFFF;
  }
  __syncthreads();
  if (tid < NPB) {   // pad fill with zero-row index
    int c = cnt[tid], p = (c + 3) & ~3;
    int base = st[tid];
    for (int k = c; k < p; ++k)
      if (base + k < BCAP_S) sorted[base + k] = n;
  }
  __syncthreads();
  int total = min(st[NPB], BCAP_S);
  for (int i = tid; i < total; i += 256) srcS[b * BCAP_S + i] = sorted[i];
  if (tid < NPB) {
    int node = b * NPB + tid;
    if (node < n) {
      nstart[node] = b * BCAP_S + st[tid];
      ncnt[node] = cnt[tid];
    }
  }
}

// ------- gather_gemm1: per-bucket gather -> LDS A-tile -> MFMA -------
// 512 threads (8 waves). Bucket b == output rows b*128..+128.
// LDS: sW 32KB | sA 16KB  => 3 blocks/CU, 24 waves/CU.
__global__ __launch_bounds__(512) void gather_gemm1(
    const unsigned short* __restrict__ xb, const int* __restrict__ nstart,
    const int* __restrict__ ncnt, const int* __restrict__ srcS,
    const unsigned short* __restrict__ Wt1, const float* __restrict__ b1,
    unsigned short* __restrict__ h, int n) {
  __shared__ unsigned short sW[16384];   // 2 x [128 col][64 k], 16B-XOR swizzled
  __shared__ unsigned short sA[8192];    // [128 row][64 ch], 16B-XOR swizzled
  int tid = threadIdx.x, lane = tid & 63, wid = tid >> 6;
  int l15 = lane & 15, g = lane >> 4;
  int b = blockIdx.x;

  // stage W early (global loads overlap the gather below)
#pragma unroll
  for (int it = 0; it < 4; ++it) {
    int i = it * 512 + tid;                 // 2048 16B chunks
    int byte = i << 4;
    int col = (byte >> 7) & 127;
    int koff = (byte & 127) ^ ((col & 7) << 4);
    int dstb = (byte & ~127) | koff;
    bf16x8 v = *(const bf16x8*)(Wt1 + i * 8);
    *(bf16x8*)((char*)sW + dstb) = v;
  }
  float bj[8];
#pragma unroll
  for (int cb = 0; cb < 8; ++cb) bj[cb] = b1[cb * 16 + l15];

  // ---- gather into sA: 8 waves x 2 nodes x 8 passes ----
  {
    int half32 = lane & 32;
    int hlane = lane & 31;
    int gg = hlane >> 3;
    int ch8 = lane & 7;
#pragma unroll 1
    for (int pass = 0; pass < 8; ++pass) {
      int dl = pass * 16 + wid * 2 + (lane >> 5);   // 0..127
      int node = b * NPB + dl;
      int s, c;
      if (node < n) { s = nstart[node]; c = ncnt[node]; }
      else          { s = b * BCAP_S;   c = 0; }
      int dpad = (c + 3) & ~3;
      float acc[8];
#pragma unroll
      for (int j = 0; j < 8; ++j) acc[j] = 0.f;
      int nit = dpad >> 2;
      int nitw = max(nit, __shfl_xor(nit, 32));
      int idx = srcS[s + hlane];
      bf16x8 cch[8];
#pragma unroll
      for (int u = 0; u < 8; ++u) {
        if (u < nitw) {
          int r = u * 4 + gg;
          int sidx = __shfl(idx, half32 + r);
          if (u < nit) cch[u] = *(const bf16x8*)(xb + (size_t)sidx * 64 + ch8 * 8);
        }
      }
#pragma unroll
      for (int u = 0; u < 8; ++u) {
        if (u < nitw && u < nit) {
#pragma unroll
          for (int j = 0; j < 8; ++j) acc[j] += bf2f((unsigned short)cch[u][j]);
        }
      }
      for (int b0 = 32; b0 < dpad; b0 += 32) {   // rare: deg > 32
        int idx2 = srcS[s + b0 + hlane];
#pragma unroll
        for (int u = 0; u < 8; ++u) {
          int r = u * 4 + gg;
          if (b0 + r < dpad) {
            int sidx = __shfl(idx2, half32 + r);
            bf16x8 v = *(const bf16x8*)(xb + (size_t)sidx * 64 + ch8 * 8);
#pragma unroll
            for (int j = 0; j < 8; ++j) acc[j] += bf2f((unsigned short)v[j]);
          }
        }
      }
#pragma unroll
      for (int m = 8; m < 32; m <<= 1) {
#pragma unroll
        for (int j = 0; j < 8; ++j) acc[j] += __shfl_xor(acc[j], m);
      }
      if (hlane < 8) {
        float inv = 1.f / (float)max(c, 1);
        bf16x8 o;
#pragma unroll
        for (int j = 0; j < 8; ++j) o[j] = (short)f2bf(acc[j] * inv);
        int byte = dl * 128 + ((ch8 * 16) ^ ((dl & 7) << 4));
        *(bf16x8*)((char*)sA + byte) = o;
      }
    }
  }
  __syncthreads();

  // ---- MFMA: wave wid -> rows wid*16..+16, all 128 cols ----
  int rowl = wid * 16 + l15;
  int growbase = b * 128 + wid * 16;
  size_t cr = (size_t)min(growbase + l15, n - 1);

  f32x4 acc[8];
#pragma unroll
  for (int cb = 0; cb < 8; ++cb) acc[cb] = (f32x4){0.f, 0.f, 0.f, 0.f};

#pragma unroll
  for (int m = 0; m < 2; ++m) {
#pragma unroll
    for (int s = 0; s < 2; ++s) {
      int ko = s * 64 + g * 16;
      bf16x8 a;
      if (m == 0) {
        int koff = ko ^ ((rowl & 7) << 4);
        a = *(const bf16x8*)((const char*)sA + rowl * 128 + koff);
      } else {
        a = *(const bf16x8*)((const char*)xb + cr * 128 + ko);
      }
#pragma unroll
      for (int cb = 0; cb < 8; ++cb) {
        int col = cb * 16 + l15;
        int koff = ko ^ ((col & 7) << 4);
        bf16x8 bb = *(const bf16x8*)((const char*)sW + m * 16384 + col * 128 + koff);
        acc[cb] = __builtin_amdgcn_mfma_f32_16x16x32_bf16(a, bb, acc[cb], 0, 0, 0);
      }
    }
  }
  int rb = growbase + g * 4;
#pragma unroll
  for (int r = 0; r < 4; ++r) {
    int row = rb + r;
    if (row < n) {
      unsigned short* hp = h + (size_t)row * 128 + l15;
#pragma unroll
      for (int cb = 0; cb < 8; ++cb) {
        float v = fmaxf(acc[cb][r] + bj[cb], 0.f);
        hp[cb * 16] = f2bf(v);
      }
    }
  }
}

// ---------------- layer 2 MFMA: [t | out] = h @ [Wl2 | Wr2] ----------------
__global__ __launch_bounds__(256) void gemm2_mfma(
    const unsigned short* __restrict__ h, const unsigned short* __restrict__ Wcat,
    const float* __restrict__ b2, unsigned short* __restrict__ t,
    float* __restrict__ outp, int n) {
  __shared__ unsigned short sW[16384];  // 32KB: [128 col][128 k], swizzled
  int tid = threadIdx.x;
  int lane = tid & 63, wid = tid >> 6;
  int l15 = lane & 15, g = lane >> 4;
#pragma unroll
  for (int it = 0; it < 8; ++it) {
    int i = it * 256 + tid;
    int byte = i << 4;
    int col = byte >> 8;
    int koff = (byte & 255) ^ ((col & 15) << 4);
    int dstb = (byte & ~255) | koff;
    bf16x8 v = *(const bf16x8*)(Wcat + i * 8);
    *(bf16x8*)((char*)sW + dstb) = v;
  }
  float bj[4];
#pragma unroll
  for (int cb = 0; cb < 4; ++cb) bj[cb] = b2[cb * 16 + l15];
  __syncthreads();

  int rowbase = blockIdx.x * 128 + wid * 32;
  int r0 = rowbase + l15, r1 = r0 + 16;
  size_t cr0 = (size_t)min(r0, n - 1), cr1 = (size_t)min(r1, n - 1);

  f32x4 acc[2][8];
#pragma unroll
  for (int fr = 0; fr < 2; ++fr)
#pragma unroll
    for (int cb = 0; cb < 8; ++cb) acc[fr][cb] = (f32x4){0.f, 0.f, 0.f, 0.f};

  const char* hb = (const char*)h;
#pragma unroll
  for (int s = 0; s < 4; ++s) {
    int ko = s * 64 + g * 16;
    bf16x8 a0 = *(const bf16x8*)(hb + cr0 * 256 + ko);
    bf16x8 a1 = *(const bf16x8*)(hb + cr1 * 256 + ko);
#pragma unroll
    for (int cb = 0; cb < 8; ++cb) {
      int col = cb * 16 + l15;
      int koff = ko ^ ((col & 15) << 4);
      bf16x8 b = *(const bf16x8*)((const char*)sW + col * 256 + koff);
      acc[0][cb] = __builtin_amdgcn_mfma_f32_16x16x32_bf16(a0, b, acc[0][cb], 0, 0, 0);
      acc[1][cb] = __builtin_amdgcn_mfma_f32_16x16x32_bf16(a1, b, acc[1][cb], 0, 0, 0);
    }
  }
#pragma unroll
  for (int fr = 0; fr < 2; ++fr) {
    int rb = rowbase + fr * 16 + g * 4;
#pragma unroll
    for (int r = 0; r < 4; ++r) {
      int row = rb + r;
      if (row < n) {
#pragma unroll
        for (int cb = 0; cb < 4; ++cb)
          t[(size_t)row * 64 + cb * 16 + l15] = f2bf(acc[fr][cb][r]);
#pragma unroll
        for (int cb = 0; cb < 4; ++cb)
          outp[(size_t)row * 64 + cb * 16 + l15] = acc[fr][cb + 4][r] + bj[cb];
      }
    }
  }
}

// ------- 2-nodes-per-wave segment-mean gather (layer 2 add) -------
__device__ __forceinline__ void gather2(
    const unsigned short* __restrict__ feat, const int* __restrict__ srcS,
    int s, int dpad, int lane, float* acc) {
  int half32 = lane & 32;
  int hlane = lane & 31;
  int g = hlane >> 3;
  int ch8 = lane & 7;
#pragma unroll
  for (int j = 0; j < 8; ++j) acc[j] = 0.f;
  int nit = dpad >> 2;
  int nitw = max(nit, __shfl_xor(nit, 32));
  int idx = srcS[s + hlane];
  bf16x8 c[8];
#pragma unroll
  for (int u = 0; u < 8; ++u) {
    if (u < nitw) {
      int r = u * 4 + g;
      int sidx = __shfl(idx, half32 + r);
      if (u < nit) c[u] = *(const bf16x8*)(feat + (size_t)sidx * 64 + ch8 * 8);
    }
  }
#pragma unroll
  for (int u = 0; u < 8; ++u) {
    if (u < nitw && u < nit) {
#pragma unroll
      for (int j = 0; j < 8; ++j) acc[j] += bf2f((unsigned short)c[u][j]);
    }
  }
  for (int b0 = 32; b0 < dpad; b0 += 32) {
    int idx2 = srcS[s + b0 + hlane];
#pragma unroll
    for (int u = 0; u < 8; ++u) {
      int r = u * 4 + g;
      if (b0 + r < dpad) {
        int sidx = __shfl(idx2, half32 + r);
        bf16x8 v = *(const bf16x8*)(feat + (size_t)sidx * 64 + ch8 * 8);
#pragma unroll
        for (int j = 0; j < 8; ++j) acc[j] += bf2f((unsigned short)v[j]);
      }
    }
  }
#pragma unroll
  for (int m = 8; m < 32; m <<= 1) {
#pragma unroll
    for (int j = 0; j < 8; ++j) acc[j] += __shfl_xor(acc[j], m);
  }
}

__global__ __launch_bounds__(256) void agg_add_fast(
    const unsigned short* __restrict__ feat, const int* __restrict__ nstart,
    const int* __restrict__ ncnt, const int* __restrict__ srcS,
    float* __restrict__ outp, int n) {
  int lane = threadIdx.x & 63, wid = threadIdx.x >> 6;
  int half = lane >> 5;
  int node = (blockIdx.x * 4 + wid) * 2 + half;
  bool live = node < n;
  int cn = live ? node : n - 1;
  int s = nstart[cn];
  int c = ncnt[cn];
  int dpad = (c + 3) & ~3;
  float acc[8];
  gather2(feat, srcS, s, dpad, lane, acc);
  float inv = 1.f / (float)max(c, 1);
  if ((lane & 31) < 8 && live) {
    float4* op = (float4*)(outp + (size_t)node * 64 + (lane & 7) * 8);
    float4 o0 = op[0], o1 = op[1];
    o0.x += acc[0] * inv; o0.y += acc[1] * inv;
    o0.z += acc[2] * inv; o0.w += acc[3] * inv;
    o1.x += acc[4] * inv; o1.y += acc[5] * inv;
    o1.z += acc[6] * inv; o1.w += acc[7] * inv;
    op[0] = o0; op[1] = o1;
  }
}

extern "C" void kernel_launch(void* const* d_in, const int* in_sizes, int n_in,
                              void* d_out, int out_size, void* d_ws, size_t ws_size,
                              hipStream_t stream) {
  const float* x   = (const float*)d_in[0];
  const int*   ei  = (const int*)d_in[1];
  const float* Wl1 = (const float*)d_in[2];
  const float* b1  = (const float*)d_in[3];
  const float* Wr1 = (const float*)d_in[4];
  const float* Wl2 = (const float*)d_in[5];
  const float* b2  = (const float*)d_in[6];
  const float* Wr2 = (const float*)d_in[7];
  float* out = (float*)d_out;

  const int n = in_sizes[0] / 64;   // 100000
  const int e = in_sizes[1] / 2;    // 1000000
  const int* src = ei;
  const int* dst = ei + e;

  char* ws = (char*)d_ws;
  size_t off = 0;
  auto take = [&](size_t bytes) { void* p = ws + off; off = (off + bytes + 255) & ~(size_t)255; return p; };
  int*            gcnt   = (int*)take((size_t)NBK * 4);
  int*            ebuf   = (int*)take((size_t)NBK * BCAP_E * 4);       // 5.0 MB
  int*            srcS   = (int*)take((size_t)NBK * BCAP_S * 4 + 256); // 6.4 MB (+slack)
  int*            nstart = (int*)take((size_t)n * 4);
  int*            ncnt   = (int*)take((size_t)n * 4);
  unsigned short* xb     = (unsigned short*)take(((size_t)n + 1) * 64 * 2);  // +zero row
  unsigned short* t      = (unsigned short*)take(((size_t)n + 1) * 64 * 2);  // +zero row
  unsigned short* h      = (unsigned short*)take((size_t)n * 128 * 2);
  unsigned short* Wt1    = (unsigned short*)take(16384 * 2);
  unsigned short* Wcat   = (unsigned short*)take(16384 * 2);

  const int total4 = n * 64 / 4;         // 1.6M
  const int CB = (total4 + 255) / 256;   // 6250

  // prep: x->bf16, W prep, gcnt zero, zero rows
  fused_misc<<<CB + 128 + 1, 256, 0, stream>>>(x, xb, total4,
                                               Wl1, Wr1, Wl2, Wr2, Wt1, Wcat,
                                               gcnt, t, n, CB);
  // bucketize edges, then per-bucket sort+pad -> global sorted CSR
  bucketize<<<(e + 4095) / 4096, 256, 0, stream>>>(src, dst, gcnt, ebuf, e);
  sort_write<<<NBK, 256, 0, stream>>>(gcnt, ebuf, srcS, nstart, ncnt, n);

  // layer 1 fused: gather + gemm1
  gather_gemm1<<<NBK, 512, 0, stream>>>(xb, nstart, ncnt, srcS, Wt1, b1, h, n);

  // layer 2
  gemm2_mfma<<<NBK, 256, 0, stream>>>(h, Wcat, b2, t, out, n);
  agg_add_fast<<<(n + 7) / 8, 256, 0, stream>>>(t, nstart, ncnt, srcS, out, n);
}

// Round 17
// 116.575 us; speedup vs baseline: 1.0639x; 1.0596x over previous
//
#include <hip/hip_runtime.h>

// GraphSAGE 2-layer, N=100000, E=1000000, 64 -> 128 -> 64.
// Round 17 = round 14 verbatim (best measured: 115.2 us).
// Zero-padded per-node edge lists (no masks in gather) + 2-nodes-per-wave
// gather. No global scatter, no float atomics. Fusion variants (r15, r16)
// both regressed: the gather phase is TLP-bound (needs 50k independent
// waves), incompatible with per-bucket fused kernels (6k waves).
//  1) fused_misc: x->bf16, W prep, gcnt zero, zero-row init
//  2) bucketize : edges -> 782 buckets of 128 dst nodes, packed (dl<<17|src)
//  3) sort_write: LDS counting sort, pad each node to x4 with ZROW=n ->
//                 srcS (coalesced), nstart, ncnt
//  4) agg_mean  : 2-nodes-per-wave gather(xb) -> agg1b bf16
//  5) gemm1_mfma: h = relu(agg1b@Wl1 + b1 + xb@Wr1)   (MFMA)
//  6) gemm2_mfma: {t, out} = h @ [Wl2 | Wr2] (+b2)    (MFMA)
//  7) agg_add   : out += mean-gather(t)

#define NPB 128       // nodes per bucket (dst >> 7)
#define NBK 782       // ceil(100000/128)
#define BCAP_E 1600   // raw bucket capacity; mean 1279, sd 36 -> +9 sigma
#define BCAP_S 2048   // sorted+padded capacity; mean ~1472, hard-clamped

typedef __attribute__((ext_vector_type(8))) short bf16x8;
typedef __attribute__((ext_vector_type(4))) float f32x4;
typedef __attribute__((ext_vector_type(4))) int int4v;

__device__ __forceinline__ float bf2f(unsigned short u) {
  return __uint_as_float(((unsigned)u) << 16);
}
__device__ __forceinline__ unsigned short f2bf(float f) {
  unsigned x = __float_as_uint(f);
  x += 0x7fffu + ((x >> 16) & 1u);   // RNE
  return (unsigned short)(x >> 16);
}

// ------- fused prep: convert_bf16 + prep_w + gcnt zero + zero-row -------
__global__ __launch_bounds__(256) void fused_misc(
    const float* __restrict__ x, unsigned short* __restrict__ xb, int total4,
    const float* __restrict__ Wl1, const float* __restrict__ Wr1,
    const float* __restrict__ Wl2, const float* __restrict__ Wr2,
    unsigned short* __restrict__ Wt1, unsigned short* __restrict__ Wcat,
    int* __restrict__ gcnt, unsigned short* __restrict__ agg1b,
    int n, int CB) {
  int b = blockIdx.x;
  if (b < CB) {
    int i = b * 256 + threadIdx.x;
    if (i < total4) {
      float4 v = ((const float4*)x)[i];
      ushort4 o;
      o.x = f2bf(v.x); o.y = f2bf(v.y); o.z = f2bf(v.z); o.w = f2bf(v.w);
      ((ushort4*)xb)[i] = o;
    }
  } else if (b < CB + 128) {
    int o = (b - CB) * 256 + threadIdx.x;   // 0..32767
    if (o < 16384) {
      int m = o >> 13, rem = o & 8191;
      int col = rem >> 6, k = rem & 63;
      const float* W = m ? Wr1 : Wl1;
      Wt1[o] = f2bf(W[k * 128 + col]);
    } else {
      int o2 = o - 16384;
      int col = o2 >> 7, k = o2 & 127;
      float v = (col < 64) ? Wl2[k * 64 + col] : Wr2[k * 64 + col - 64];
      Wcat[o2] = f2bf(v);
    }
  } else {
    for (int i = threadIdx.x; i < NBK; i += 256) gcnt[i] = 0;
    // zero feature row at index n (gather pad target); survives: only
    // rows < n are written by agg_mean/gemm2 afterwards.
    if (threadIdx.x < 32) {
      ((unsigned*)(xb + (size_t)n * 64))[threadIdx.x] = 0;
      ((unsigned*)(agg1b + (size_t)n * 64))[threadIdx.x] = 0;
    }
  }
}

// ---------------- bucketize: edges -> 782 buckets, packed 4B ----------------
__global__ __launch_bounds__(256) void bucketize(
    const int* __restrict__ src, const int* __restrict__ dst,
    int* __restrict__ gcnt, int* __restrict__ ebuf, int e) {
  __shared__ int lcnt[NBK], lbase[NBK];
  for (int i = threadIdx.x; i < NBK; i += 256) lcnt[i] = 0;
  __syncthreads();
  int pk[16], bk[16];
  int nv = 0;
  int base = blockIdx.x * 4096 + threadIdx.x * 4;
#pragma unroll
  for (int c = 0; c < 4; ++c) {
    int i = base + c * 1024;
    if (i + 4 <= e) {
      int4v sv = *(const int4v*)(src + i);
      int4v dv = *(const int4v*)(dst + i);
#pragma unroll
      for (int j = 0; j < 4; ++j) {
        bk[nv] = dv[j] >> 7;
        pk[nv] = ((dv[j] & 127) << 17) | sv[j];
        ++nv;
      }
    } else if (i < e) {
      for (int i2 = i; i2 < e; ++i2) {
        int dj = dst[i2], sj = src[i2];
        bk[nv] = dj >> 7;
        pk[nv] = ((dj & 127) << 17) | sj;
        ++nv;
      }
    }
  }
  for (int k = 0; k < nv; ++k) atomicAdd(&lcnt[bk[k]], 1);
  __syncthreads();
  for (int i = threadIdx.x; i < NBK; i += 256) {
    lbase[i] = atomicAdd(&gcnt[i], lcnt[i]);
    lcnt[i] = 0;   // reuse as cursor
  }
  __syncthreads();
  for (int k = 0; k < nv; ++k) {
    int off = lbase[bk[k]] + atomicAdd(&lcnt[bk[k]], 1);
    if (off < BCAP_E) ebuf[bk[k] * BCAP_E + off] = pk[k];
  }
}

// ------- sort_write: LDS counting sort + pad-to-x4 -> global CSR -------
// srcS[b*BCAP_S + pos] coalesced; nstart[node]=b*BCAP_S+st, ncnt=real count.
// Pad slots hold index n (zero feature row).
__global__ __launch_bounds__(256) void sort_write(
    const int* __restrict__ gcnt, const int* __restrict__ ebuf,
    int* __restrict__ srcS, int* __restrict__ nstart, int* __restrict__ ncnt,
    int n) {
  __shared__ int cnt[NPB], cur[NPB], st[NPB + 1], sorted[BCAP_S];
  int tid = threadIdx.x, lane = tid & 63, wid = tid >> 6;
  int b = blockIdx.x;
  if (tid < NPB) { cnt[tid] = 0; cur[tid] = 0; }
  __syncthreads();
  int ecnt = min(gcnt[b], BCAP_E);
  const int* eb = ebuf + b * BCAP_E;
  for (int i = tid; i < ecnt; i += 256) atomicAdd(&cnt[eb[i] >> 17], 1);
  __syncthreads();
  if (wid == 0) {   // exclusive scan of 128 PADDED counts with one wave
    int i0 = (cnt[lane] + 3) & ~3, i1 = (cnt[64 + lane] + 3) & ~3;
#pragma unroll
    for (int off = 1; off < 64; off <<= 1) {
      int u = __shfl_up(i0, off);
      if (lane >= off) i0 += u;
    }
    int t0 = __shfl(i0, 63);
#pragma unroll
    for (int off = 1; off < 64; off <<= 1) {
      int u = __shfl_up(i1, off);
      if (lane >= off) i1 += u;
    }
    st[lane + 1] = i0;
    st[64 + lane + 1] = t0 + i1;
    if (lane == 0) st[0] = 0;
  }
  __syncthreads();
  for (int i = tid; i < ecnt; i += 256) {
    int pk = eb[i];
    int dl = pk >> 17;
    int pos = st[dl] + atomicAdd(&cur[dl], 1);
    if (pos < BCAP_S) sorted[pos] = pk & 0x1FFFF;
  }
  __syncthreads();
  if (tid < NPB) {   // pad fill with zero-row index
    int c = cnt[tid], p = (c + 3) & ~3;
    int base = st[tid];
    for (int k = c; k < p; ++k)
      if (base + k < BCAP_S) sorted[base + k] = n;
  }
  __syncthreads();
  int total = min(st[NPB], BCAP_S);
  for (int i = tid; i < total; i += 256) srcS[b * BCAP_S + i] = sorted[i];
  if (tid < NPB) {
    int node = b * NPB + tid;
    if (node < n) {
      nstart[node] = b * BCAP_S + st[tid];
      ncnt[node] = cnt[tid];
    }
  }
}

// ------- 2-nodes-per-wave segment-mean gather core -------
// lanes 0-31: node A, lanes 32-63: node B. Within a half: group = hlane>>3
// (4 rows per chunk), channels (lane&7)*8..+8 as bf16x8 (16B/lane).
// dpad is a multiple of 4; pad entries point at the zero row -> no masks.
__device__ __forceinline__ void gather2(
    const unsigned short* __restrict__ feat, const int* __restrict__ srcS,
    int s, int dpad, int lane, float* acc) {
  int half32 = lane & 32;
  int hlane = lane & 31;
  int g = hlane >> 3;
  int ch8 = lane & 7;
#pragma unroll
  for (int j = 0; j < 8; ++j) acc[j] = 0.f;
  int nit = dpad >> 2;                       // chunks of 4 rows (this half)
  int nitw = max(nit, __shfl_xor(nit, 32));  // wave loop bound
  int idx = srcS[s + hlane];                 // first 32 indices of this node
  bf16x8 c[8];
  // load phase: all chunk loads issued before any accumulate
#pragma unroll
  for (int u = 0; u < 8; ++u) {
    if (u < nitw) {
      int r = u * 4 + g;                     // r <= 31
      int sidx = __shfl(idx, half32 + r);
      if (u < nit) c[u] = *(const bf16x8*)(feat + (size_t)sidx * 64 + ch8 * 8);
    }
  }
  // accumulate phase (no validity masks: pads read the zero row)
#pragma unroll
  for (int u = 0; u < 8; ++u) {
    if (u < nitw && u < nit) {
#pragma unroll
      for (int j = 0; j < 8; ++j) acc[j] += bf2f((unsigned short)c[u][j]);
    }
  }
  // rare tail: dpad > 32
  for (int b0 = 32; b0 < dpad; b0 += 32) {
    int idx2 = srcS[s + b0 + hlane];
#pragma unroll
    for (int u = 0; u < 8; ++u) {
      int r = u * 4 + g;
      if (b0 + r < dpad) {
        int sidx = __shfl(idx2, half32 + r);
        bf16x8 v = *(const bf16x8*)(feat + (size_t)sidx * 64 + ch8 * 8);
#pragma unroll
        for (int j = 0; j < 8; ++j) acc[j] += bf2f((unsigned short)v[j]);
      }
    }
  }
  // fold the 4 row-groups within each half (2 rounds)
#pragma unroll
  for (int m = 8; m < 32; m <<= 1) {
#pragma unroll
    for (int j = 0; j < 8; ++j) acc[j] += __shfl_xor(acc[j], m);
  }
}

__global__ __launch_bounds__(256) void agg_mean_fast(
    const unsigned short* __restrict__ feat, const int* __restrict__ nstart,
    const int* __restrict__ ncnt, const int* __restrict__ srcS,
    unsigned short* __restrict__ outp, int n) {
  int lane = threadIdx.x & 63, wid = threadIdx.x >> 6;
  int half = lane >> 5;
  int node = (blockIdx.x * 4 + wid) * 2 + half;
  bool live = node < n;
  int cn = live ? node : n - 1;
  int s = nstart[cn];
  int c = ncnt[cn];
  int dpad = (c + 3) & ~3;
  float acc[8];
  gather2(feat, srcS, s, dpad, lane, acc);
  float inv = 1.f / (float)max(c, 1);
  if ((lane & 31) < 8 && live) {
    bf16x8 o;
#pragma unroll
    for (int j = 0; j < 8; ++j) o[j] = (short)f2bf(acc[j] * inv);
    *(bf16x8*)(outp + (size_t)node * 64 + (lane & 7) * 8) = o;
  }
}

__global__ __launch_bounds__(256) void agg_add_fast(
    const unsigned short* __restrict__ feat, const int* __restrict__ nstart,
    const int* __restrict__ ncnt, const int* __restrict__ srcS,
    float* __restrict__ outp, int n) {
  int lane = threadIdx.x & 63, wid = threadIdx.x >> 6;
  int half = lane >> 5;
  int node = (blockIdx.x * 4 + wid) * 2 + half;
  bool live = node < n;
  int cn = live ? node : n - 1;
  int s = nstart[cn];
  int c = ncnt[cn];
  int dpad = (c + 3) & ~3;
  float acc[8];
  gather2(feat, srcS, s, dpad, lane, acc);
  float inv = 1.f / (float)max(c, 1);
  if ((lane & 31) < 8 && live) {
    float4* op = (float4*)(outp + (size_t)node * 64 + (lane & 7) * 8);
    float4 o0 = op[0], o1 = op[1];
    o0.x += acc[0] * inv; o0.y += acc[1] * inv;
    o0.z += acc[2] * inv; o0.w += acc[3] * inv;
    o1.x += acc[4] * inv; o1.y += acc[5] * inv;
    o1.z += acc[6] * inv; o1.w += acc[7] * inv;
    op[0] = o0; op[1] = o1;
  }
}

// ---------------- layer 1 MFMA: h = relu(agg@Wl1 + b1 + xb@Wr1) ----------------
__global__ __launch_bounds__(256) void gemm1_mfma(
    const unsigned short* __restrict__ agg, const unsigned short* __restrict__ xb,
    const unsigned short* __restrict__ Wt1, const float* __restrict__ b1,
    unsigned short* __restrict__ h, int n) {
  __shared__ unsigned short sW[16384];  // 32KB: 2 x [128 col][64 k], 16B-XOR swizzled
  int tid = threadIdx.x;
  int lane = tid & 63, wid = tid >> 6;
  int l15 = lane & 15, g = lane >> 4;
#pragma unroll
  for (int it = 0; it < 8; ++it) {
    int i = it * 256 + tid;
    int byte = i << 4;
    int col = (byte >> 7) & 127;
    int koff = (byte & 127) ^ ((col & 7) << 4);
    int dstb = (byte & ~127) | koff;
    bf16x8 v = *(const bf16x8*)(Wt1 + i * 8);
    *(bf16x8*)((char*)sW + dstb) = v;
  }
  float bj[8];
#pragma unroll
  for (int cb = 0; cb < 8; ++cb) bj[cb] = b1[cb * 16 + l15];
  __syncthreads();

  int rowbase = blockIdx.x * 128 + wid * 32;
  int r0 = rowbase + l15, r1 = r0 + 16;
  size_t cr0 = (size_t)min(r0, n - 1), cr1 = (size_t)min(r1, n - 1);

  f32x4 acc[2][8];
#pragma unroll
  for (int fr = 0; fr < 2; ++fr)
#pragma unroll
    for (int cb = 0; cb < 8; ++cb) acc[fr][cb] = (f32x4){0.f, 0.f, 0.f, 0.f};

#pragma unroll
  for (int m = 0; m < 2; ++m) {
    const char* base = m ? (const char*)xb : (const char*)agg;
#pragma unroll
    for (int s = 0; s < 2; ++s) {
      int ko = s * 64 + g * 16;
      bf16x8 a0 = *(const bf16x8*)(base + cr0 * 128 + ko);
      bf16x8 a1 = *(const bf16x8*)(base + cr1 * 128 + ko);
#pragma unroll
      for (int cb = 0; cb < 8; ++cb) {
        int col = cb * 16 + l15;
        int koff = ko ^ ((col & 7) << 4);
        bf16x8 b = *(const bf16x8*)((const char*)sW + m * 16384 + col * 128 + koff);
        acc[0][cb] = __builtin_amdgcn_mfma_f32_16x16x32_bf16(a0, b, acc[0][cb], 0, 0, 0);
        acc[1][cb] = __builtin_amdgcn_mfma_f32_16x16x32_bf16(a1, b, acc[1][cb], 0, 0, 0);
      }
    }
  }
#pragma unroll
  for (int fr = 0; fr < 2; ++fr) {
    int rb = rowbase + fr * 16 + g * 4;
#pragma unroll
    for (int r = 0; r < 4; ++r) {
      int row = rb + r;
      if (row < n) {
        unsigned short* hp = h + (size_t)row * 128 + l15;
#pragma unroll
        for (int cb = 0; cb < 8; ++cb) {
          float v = fmaxf(acc[fr][cb][r] + bj[cb], 0.f);
          hp[cb * 16] = f2bf(v);
        }
      }
    }
  }
}

// ---------------- layer 2 MFMA: [t | out] = h @ [Wl2 | Wr2] ----------------
__global__ __launch_bounds__(256) void gemm2_mfma(
    const unsigned short* __restrict__ h, const unsigned short* __restrict__ Wcat,
    const float* __restrict__ b2, unsigned short* __restrict__ t,
    float* __restrict__ outp, int n) {
  __shared__ unsigned short sW[16384];  // 32KB: [128 col][128 k], swizzled
  int tid = threadIdx.x;
  int lane = tid & 63, wid = tid >> 6;
  int l15 = lane & 15, g = lane >> 4;
#pragma unroll
  for (int it = 0; it < 8; ++it) {
    int i = it * 256 + tid;
    int byte = i << 4;
    int col = byte >> 8;
    int koff = (byte & 255) ^ ((col & 15) << 4);
    int dstb = (byte & ~255) | koff;
    bf16x8 v = *(const bf16x8*)(Wcat + i * 8);
    *(bf16x8*)((char*)sW + dstb) = v;
  }
  float bj[4];
#pragma unroll
  for (int cb = 0; cb < 4; ++cb) bj[cb] = b2[cb * 16 + l15];
  __syncthreads();

  int rowbase = blockIdx.x * 128 + wid * 32;
  int r0 = rowbase + l15, r1 = r0 + 16;
  size_t cr0 = (size_t)min(r0, n - 1), cr1 = (size_t)min(r1, n - 1);

  f32x4 acc[2][8];
#pragma unroll
  for (int fr = 0; fr < 2; ++fr)
#pragma unroll
    for (int cb = 0; cb < 8; ++cb) acc[fr][cb] = (f32x4){0.f, 0.f, 0.f, 0.f};

  const char* hb = (const char*)h;
#pragma unroll
  for (int s = 0; s < 4; ++s) {
    int ko = s * 64 + g * 16;
    bf16x8 a0 = *(const bf16x8*)(hb + cr0 * 256 + ko);
    bf16x8 a1 = *(const bf16x8*)(hb + cr1 * 256 + ko);
#pragma unroll
    for (int cb = 0; cb < 8; ++cb) {
      int col = cb * 16 + l15;
      int koff = ko ^ ((col & 15) << 4);
      bf16x8 b = *(const bf16x8*)((const char*)sW + col * 256 + koff);
      acc[0][cb] = __builtin_amdgcn_mfma_f32_16x16x32_bf16(a0, b, acc[0][cb], 0, 0, 0);
      acc[1][cb] = __builtin_amdgcn_mfma_f32_16x16x32_bf16(a1, b, acc[1][cb], 0, 0, 0);
    }
  }
#pragma unroll
  for (int fr = 0; fr < 2; ++fr) {
    int rb = rowbase + fr * 16 + g * 4;
#pragma unroll
    for (int r = 0; r < 4; ++r) {
      int row = rb + r;
      if (row < n) {
#pragma unroll
        for (int cb = 0; cb < 4; ++cb)
          t[(size_t)row * 64 + cb * 16 + l15] = f2bf(acc[fr][cb][r]);
#pragma unroll
        for (int cb = 0; cb < 4; ++cb)
          outp[(size_t)row * 64 + cb * 16 + l15] = acc[fr][cb + 4][r] + bj[cb];
      }
    }
  }
}

extern "C" void kernel_launch(void* const* d_in, const int* in_sizes, int n_in,
                              void* d_out, int out_size, void* d_ws, size_t ws_size,
                              hipStream_t stream) {
  const float* x   = (const float*)d_in[0];
  const int*   ei  = (const int*)d_in[1];
  const float* Wl1 = (const float*)d_in[2];
  const float* b1  = (const float*)d_in[3];
  const float* Wr1 = (const float*)d_in[4];
  const float* Wl2 = (const float*)d_in[5];
  const float* b2  = (const float*)d_in[6];
  const float* Wr2 = (const float*)d_in[7];
  float* out = (float*)d_out;

  const int n = in_sizes[0] / 64;   // 100000
  const int e = in_sizes[1] / 2;    // 1000000
  const int* src = ei;
  const int* dst = ei + e;

  char* ws = (char*)d_ws;
  size_t off = 0;
  auto take = [&](size_t bytes) { void* p = ws + off; off = (off + bytes + 255) & ~(size_t)255; return p; };
  int*            gcnt   = (int*)take((size_t)NBK * 4);
  int*            ebuf   = (int*)take((size_t)NBK * BCAP_E * 4);       // 5.0 MB
  int*            srcS   = (int*)take((size_t)NBK * BCAP_S * 4 + 256); // 6.4 MB (+slack)
  int*            nstart = (int*)take((size_t)n * 4);
  int*            ncnt   = (int*)take((size_t)n * 4);
  unsigned short* xb     = (unsigned short*)take(((size_t)n + 1) * 64 * 2);  // +zero row
  unsigned short* agg1b  = (unsigned short*)take(((size_t)n + 1) * 64 * 2);  // +zero row
  unsigned short* h      = (unsigned short*)take((size_t)n * 128 * 2);
  unsigned short* t      = agg1b;   // alias: agg1b dead after gemm1; zero row preserved
  unsigned short* Wt1    = (unsigned short*)take(16384 * 2);
  unsigned short* Wcat   = (unsigned short*)take(16384 * 2);

  const int NTILE = (n + 127) / 128;     // 782
  const int total4 = n * 64 / 4;         // 1.6M
  const int CB = (total4 + 255) / 256;   // 6250

  // prep: x->bf16, W prep, gcnt zero, zero rows
  fused_misc<<<CB + 128 + 1, 256, 0, stream>>>(x, xb, total4,
                                               Wl1, Wr1, Wl2, Wr2, Wt1, Wcat,
                                               gcnt, agg1b, n, CB);
  // bucketize edges, then per-bucket sort+pad -> global sorted CSR
  bucketize<<<(e + 4095) / 4096, 256, 0, stream>>>(src, dst, gcnt, ebuf, e);
  sort_write<<<NBK, 256, 0, stream>>>(gcnt, ebuf, srcS, nstart, ncnt, n);

  // layer 1
  agg_mean_fast<<<(n + 7) / 8, 256, 0, stream>>>(xb, nstart, ncnt, srcS, agg1b, n);
  gemm1_mfma<<<NTILE, 256, 0, stream>>>(agg1b, xb, Wt1, b1, h, n);

  // layer 2
  gemm2_mfma<<<NTILE, 256, 0, stream>>>(h, Wcat, b2, t, out, n);
  agg_add_fast<<<(n + 7) / 8, 256, 0, stream>>>(t, nstart, ncnt, srcS, out, n);
}